// Round 1
// baseline (561.941 us; speedup 1.0000x reference)
//
#include <hip/hip_runtime.h>

#define B_   32
#define S_   1024
#define V_   32000
#define E_   256
#define H_   512
#define D2_  1124
#define IN_  1380
#define INP_ 1408
#define G3_  1536
#define NV_  33024   // V + S
#define VO_  32012   // V + MAX_OOVS
#define NKT_ 36      // K tiles of 32 covering 1152 (1124 padded)

typedef __bf16 bf16x8 __attribute__((ext_vector_type(8)));
typedef float  f32x4  __attribute__((ext_vector_type(4)));

static __device__ __forceinline__ unsigned short f2bf(float f) {
    union { float f; unsigned int u; } v; v.f = f;
    unsigned int u = v.u;
    unsigned int r = (u + 0x7FFFu + ((u >> 16) & 1u)) >> 16;  // RNE
    return (unsigned short)r;
}

// ---------------- order handling: effective prev_state / weighted ----------------
__global__ void k_prep0(const int* order, const float* prev, const float* weighted,
                        const float* encoded, const float* bin,
                        const float* Ws_w, const float* Ws_b,
                        float* prev_eff, float* weff) {
    int b = blockIdx.x, t = threadIdx.x;
    if (order[0] != 0) {
        for (int i = t; i < H_;  i += 256) prev_eff[b * H_ + i] = prev[b * H_ + i];
        for (int i = t; i < D2_; i += 256) weff[b * D2_ + i] = weighted[b * D2_ + i];
    } else {
        for (int i = t; i < D2_; i += 256) weff[b * D2_ + i] = 0.0f;
        const float* encrow = encoded + ((size_t)(b * S_ + (S_ - 1))) * 1024;
        float bv = bin[b * S_ + (S_ - 1)];
        for (int h = t; h < H_; h += 256) {
            float acc = Ws_b[h];
            const float* wr = Ws_w + (size_t)h * D2_;
            for (int d = 0; d < 1024; d++) acc += encrow[d] * wr[d];
            for (int d = 1024; d < D2_; d++) acc += bv * wr[d];
            prev_eff[b * H_ + h] = acc;
        }
    }
}

// ---------------- build x = [emb, weighted], padded to 1408 with zeros ----------------
__global__ void k_build_x(const int* input_idx, const float* embed, const float* weff, float* x) {
    int idx = blockIdx.x * 256 + threadIdx.x;   // 32*1408 exact
    int b = idx / INP_, d = idx % INP_;
    float v;
    if (d < E_)        v = embed[(size_t)input_idx[b] * E_ + d];
    else if (d < IN_)  v = weff[b * D2_ + (d - E_)];
    else               v = 0.0f;
    x[idx] = v;
}

// ---------------- pack Wc_w into MFMA B-fragment layout (bf16) ----------------
// bpack[((kt*32 + ht)*64 + lane)*8 + j] = Wc_w[ht*16 + (lane&15)][kt*32 + (lane>>4)*8 + j]
__global__ void k_pack_wc(const float* Wc_w, unsigned short* bpack) {
    int idx = blockIdx.x * 256 + threadIdx.x;   // 589824 exact
    int j = idx & 7, lane = (idx >> 3) & 63, ht = (idx >> 9) & 31, kt = idx >> 14;
    int h = ht * 16 + (lane & 15);
    int k = kt * 32 + (lane >> 4) * 8 + j;
    float v = (k < D2_) ? Wc_w[(size_t)h * D2_ + k] : 0.0f;
    bpack[idx] = f2bf(v);
}

// ---------------- gi = x @ W_ih.T + b_ih ----------------
__global__ void k_gi(const float* x, const float* W_ih, const float* b_ih, float* gi) {
    extern __shared__ float smemF[];            // 16 * 1408 floats
    int t = threadIdx.x;
    int bh = blockIdx.x & 1;
    int hq = blockIdx.x >> 1;
    const float4* xg = (const float4*)(x + (size_t)bh * 16 * INP_);
    float4* xl4 = (float4*)smemF;
    for (int j = t; j < 16 * INP_ / 4; j += 256) xl4[j] = xg[j];
    __syncthreads();
    int w = t >> 6, l = t & 63;
    int h3 = hq * 4 + w;
    const float* wr = W_ih + (size_t)h3 * IN_;
    float4 wv[6];
#pragma unroll
    for (int i = 0; i < 6; i++) {
        int k = 4 * l + 256 * i;
        if (k + 3 < IN_) wv[i] = *(const float4*)(wr + k);
        else {
            float a0 = (k     < IN_) ? wr[k]     : 0.f;
            float a1 = (k + 1 < IN_) ? wr[k + 1] : 0.f;
            float a2 = (k + 2 < IN_) ? wr[k + 2] : 0.f;
            float a3 = (k + 3 < IN_) ? wr[k + 3] : 0.f;
            wv[i] = make_float4(a0, a1, a2, a3);
        }
    }
    float bias = b_ih[h3];
    for (int bb = 0; bb < 16; bb++) {
        const float4* xr = xl4 + bb * (INP_ / 4);
        float p = 0.f;
#pragma unroll
        for (int i = 0; i < 6; i++) {
            int k = 4 * l + 256 * i;
            if (k < INP_) {
                float4 xv = xr[l + 64 * i];
                p += wv[i].x * xv.x + wv[i].y * xv.y + wv[i].z * xv.z + wv[i].w * xv.w;
            }
        }
#pragma unroll
        for (int off = 32; off >= 1; off >>= 1) p += __shfl_xor(p, off, 64);
        if (l == 0) gi[(bh * 16 + bb) * G3_ + h3] = p + bias;
    }
}

// ---------------- gh = prev_eff @ W_hh.T + b_hh ----------------
__global__ void k_gh(const float* prev_eff, const float* W_hh, const float* b_hh, float* gh) {
    extern __shared__ float smemF[];            // 32*512 floats
    int t = threadIdx.x;
    const float4* pg = (const float4*)prev_eff;
    float4* pl4 = (float4*)smemF;
    for (int j = t; j < B_ * H_ / 4; j += 256) pl4[j] = pg[j];
    __syncthreads();
    int w = t >> 6, l = t & 63;
    int h3 = blockIdx.x * 4 + w;
    const float* wr = W_hh + (size_t)h3 * H_;
    float4 w0 = *(const float4*)(wr + 4 * l);
    float4 w1 = *(const float4*)(wr + 256 + 4 * l);
    float bias = b_hh[h3];
    for (int bb = 0; bb < B_; bb++) {
        const float* pr = smemF + bb * H_;
        float4 s0 = *(const float4*)(pr + 4 * l);
        float4 s1 = *(const float4*)(pr + 256 + 4 * l);
        float p = w0.x * s0.x + w0.y * s0.y + w0.z * s0.z + w0.w * s0.w
                + w1.x * s1.x + w1.y * s1.y + w1.z * s1.z + w1.w * s1.w;
#pragma unroll
        for (int off = 32; off >= 1; off >>= 1) p += __shfl_xor(p, off, 64);
        if (l == 0) gh[bb * G3_ + h3] = p + bias;
    }
}

// ---------------- GRU gates -> state ----------------
__global__ void k_gate(const float* gi, const float* gh, const float* prev_eff,
                       float* state, float* out_state) {
    int idx = blockIdx.x * 256 + threadIdx.x;   // 16384 exact
    int b = idx >> 9, h = idx & 511;
    float ir = gi[b * G3_ + h],           hr = gh[b * G3_ + h];
    float iz = gi[b * G3_ + H_ + h],      hz = gh[b * G3_ + H_ + h];
    float in_ = gi[b * G3_ + 2 * H_ + h], hn = gh[b * G3_ + 2 * H_ + h];
    float r = 1.0f / (1.0f + expf(-(ir + hr)));
    float z = 1.0f / (1.0f + expf(-(iz + hz)));
    float n = tanhf(in_ + r * hn);
    float st = (1.0f - z) * n + z * prev_eff[idx];
    state[idx] = st;
    out_state[idx] = st;
}

// ---------------- score_g = state @ Wo_w.T + Wo_b ----------------
__global__ void k_scoreg(const float* state, const float* Wo_w, const float* Wo_b, float* scores) {
    extern __shared__ float smemF[];            // 32*512 floats
    int t = threadIdx.x;
    const float4* sg = (const float4*)state;
    float4* sl4 = (float4*)smemF;
    for (int j = t; j < B_ * H_ / 4; j += 256) sl4[j] = sg[j];
    __syncthreads();
    int l = t & 63;
    int gw = blockIdx.x * 4 + (t >> 6);
    for (int n = gw; n < V_; n += gridDim.x * 4) {
        const float* wr = Wo_w + (size_t)n * H_;
        float4 w0 = *(const float4*)(wr + 4 * l);
        float4 w1 = *(const float4*)(wr + 256 + 4 * l);
        float wb = Wo_b[n];
        for (int bb = 0; bb < B_; bb++) {
            const float* sr = smemF + bb * H_;
            float4 s0 = *(const float4*)(sr + 4 * l);
            float4 s1 = *(const float4*)(sr + 256 + 4 * l);
            float p = w0.x * s0.x + w0.y * s0.y + w0.z * s0.z + w0.w * s0.w
                    + w1.x * s1.x + w1.y * s1.y + w1.z * s1.z + w1.w * s1.w;
#pragma unroll
            for (int off = 32; off >= 1; off >>= 1) p += __shfl_xor(p, off, 64);
            if (l == 0) scores[bb * NV_ + n] = p + wb;
        }
    }
}

// ---------------- fused sc = tanh(enc@Wc_w.T + Wc_b); score_c = tanh(sc . state) + mask --------
// grid: 32 b * 16 s-tiles(64), block 512 threads (8 waves); wave w covers h in [w*64, w*64+64)
__global__ void __launch_bounds__(512) k_sc(
    const float* encoded, const float* bin, const unsigned short* bpack,
    const float* Wc_b, const float* state, const int* enc_idx, float* scores) {
    __shared__ unsigned short Albf[64 * 40];    // 64 s rows, 32 k + pad 8 (16B-aligned rows)
    __shared__ float partL[8][64];
    int t = threadIdx.x;
    int b = blockIdx.x >> 4;
    int s0 = (blockIdx.x & 15) * 64;
    int w = t >> 6, l = t & 63;
    int q = l >> 4, m = l & 15;

    f32x4 acc[4][4];
#pragma unroll
    for (int i = 0; i < 4; i++)
#pragma unroll
        for (int j2 = 0; j2 < 4; j2++) { acc[i][j2][0]=0.f; acc[i][j2][1]=0.f; acc[i][j2][2]=0.f; acc[i][j2][3]=0.f; }

    int s_l = t >> 3, k4 = (t & 7) * 4;
    const float* encbase = encoded + ((size_t)(b * S_ + s0 + s_l)) * 1024;
    float binv = bin[b * S_ + s0 + s_l];

    for (int kt = 0; kt < NKT_; kt++) {
        __syncthreads();
        int k = kt * 32 + k4;
        float v0, v1, v2, v3;
        if (kt < 32) {
            float4 e4 = *(const float4*)(encbase + k);
            v0 = e4.x; v1 = e4.y; v2 = e4.z; v3 = e4.w;
        } else {
            v0 = (k     < D2_ + 1024 - 1024) || (k     < D2_) ? ((k     < D2_) ? binv : 0.f) : 0.f;
            v0 = (k     < D2_) ? binv : 0.f;
            v1 = (k + 1 < D2_) ? binv : 0.f;
            v2 = (k + 2 < D2_) ? binv : 0.f;
            v3 = (k + 3 < D2_) ? binv : 0.f;
        }
        ushort4 pk;
        pk.x = f2bf(v0); pk.y = f2bf(v1); pk.z = f2bf(v2); pk.w = f2bf(v3);
        *(ushort4*)&Albf[s_l * 40 + k4] = pk;
        __syncthreads();

        bf16x8 av[4], bv[4];
#pragma unroll
        for (int st = 0; st < 4; st++)
            av[st] = *(const bf16x8*)&Albf[(st * 16 + m) * 40 + q * 8];
#pragma unroll
        for (int jj = 0; jj < 4; jj++)
            bv[jj] = *(const bf16x8*)&bpack[(((size_t)kt * 32 + (w * 4 + jj)) * 64 + l) * 8];
#pragma unroll
        for (int st = 0; st < 4; st++)
#pragma unroll
            for (int jj = 0; jj < 4; jj++)
                acc[st][jj] = __builtin_amdgcn_mfma_f32_16x16x32_bf16(av[st], bv[jj], acc[st][jj], 0, 0, 0);
    }

    // epilogue: val(s) = sum_h tanh(sc + bias_h) * state_h, reduce 16 lanes + 8 waves
    float hbias[4], hstate[4];
#pragma unroll
    for (int jj = 0; jj < 4; jj++) {
        int h = w * 64 + jj * 16 + m;
        hbias[jj]  = Wc_b[h];
        hstate[jj] = state[b * H_ + h];
    }
#pragma unroll
    for (int st = 0; st < 4; st++) {
#pragma unroll
        for (int r = 0; r < 4; r++) {
            float val = 0.f;
#pragma unroll
            for (int jj = 0; jj < 4; jj++)
                val += tanhf(acc[st][jj][r] + hbias[jj]) * hstate[jj];
            val += __shfl_xor(val, 1, 64);
            val += __shfl_xor(val, 2, 64);
            val += __shfl_xor(val, 4, 64);
            val += __shfl_xor(val, 8, 64);
            if (m == 0) partL[w][st * 16 + q * 4 + r] = val;
        }
    }
    __syncthreads();
    if (t < 64) {
        float tot = 0.f;
#pragma unroll
        for (int ww = 0; ww < 8; ww++) tot += partL[ww][t];
        int s = s0 + t;
        int ei = enc_idx[b * S_ + s];
        scores[b * NV_ + V_ + s] = tanhf(tot) + (ei == 0 ? -1000.0f : 0.0f);
    }
}

// ---------------- exp pass (in place) + partial sums ----------------
__global__ void k_exp(float* scores, float* partA, float* partC) {
    int blk = blockIdx.x;                       // 512 = 32 b * 16 chunks
    int b = blk >> 4, c = blk & 15;
    int t = threadIdx.x;
    float sa = 0.f, sc2 = 0.f;
    int base = b * NV_ + c * 2064;
    for (int i = t; i < 2064; i += 256) {
        float e = expf(scores[base + i]);
        scores[base + i] = e;
        sa += e;
        if (c * 2064 + i >= V_) sc2 += e;
    }
#pragma unroll
    for (int off = 32; off >= 1; off >>= 1) {
        sa  += __shfl_xor(sa, off, 64);
        sc2 += __shfl_xor(sc2, off, 64);
    }
    __shared__ float rA[4], rC[4];
    int w = t >> 6, l = t & 63;
    if (l == 0) { rA[w] = sa; rC[w] = sc2; }
    __syncthreads();
    if (t == 0) {
        partA[blk] = rA[0] + rA[1] + rA[2] + rA[3];
        partC[blk] = rC[0] + rC[1] + rC[2] + rC[3];
    }
}

// ---------------- combine: row sums, global c-sum, match count/list ----------------
__global__ void k_combine(const float* partA, const float* partC, float* rowinv, float* invgc,
                          int* cnt, int* list, const int* enc_idx, const int* input_idx) {
    __shared__ float rs[32], rc[32];
    int t = threadIdx.x;
    if (t < 32) {
        float a = 0.f, c = 0.f;
        for (int j = 0; j < 16; j++) { a += partA[t * 16 + j]; c += partC[t * 16 + j]; }
        rs[t] = a; rc[t] = c;
        rowinv[t] = 1.0f / a;
        cnt[t] = 0;
    }
    __syncthreads();
    if (t == 0) {
        float g = 0.f;
        for (int b = 0; b < 32; b++) g += rc[b] / rs[b];
        invgc[0] = 1.0f / g;
    }
    for (int i = t; i < B_ * S_; i += 512) {
        int b = i >> 10;
        if (enc_idx[i] == input_idx[b]) {
            int p = atomicAdd(&cnt[b], 1);
            list[b * S_ + p] = i & 1023;
        }
    }
}

// ---------------- normalize: prob_g -> out, prob_c -> ws ----------------
__global__ void k_write(const float* scores, const float* rowinv, float* out, float* probc) {
    int idx = blockIdx.x * 256 + threadIdx.x;   // 32*33024 exact
    int b = idx / NV_, v = idx - b * NV_;
    float p = scores[idx] * rowinv[b];
    if (v < V_) out[b * VO_ + v] = p;
    else        probc[b * S_ + (v - V_)] = p;
}

__global__ void k_oov(float* out) {
    int idx = blockIdx.x * 256 + threadIdx.x;
    if (idx < B_ * 12) {
        int b = idx / 12, j = idx - b * 12;
        out[b * VO_ + V_ + j] = 0.0001f;
    }
}

// ---------------- scatter prob_c into out ----------------
__global__ void k_scatter(const float* probc, const int* enc_idx, float* out) {
    int idx = blockIdx.x * 256 + threadIdx.x;   // 32768 exact
    int b = idx >> 10;
    atomicAdd(&out[b * VO_ + enc_idx[idx]], probc[idx]);
}

// ---------------- weighted_out via sparse match list ----------------
__global__ void k_wo(const float* probc, const int* list, const int* cnt, const float* invgc,
                     const float* encoded, const float* bin, float* out2) {
    int b = blockIdx.x, t = threadIdx.x;
    __shared__ float aL[1024];
    __shared__ int   sL[1024];
    int n = cnt[b];
    float scale = invgc[0] * (n > 1 ? 1.0f / (float)n : 1.0f);
    for (int i = t; i < n; i += 256) {
        int s = list[b * S_ + i];
        sL[i] = s;
        aL[i] = probc[b * S_ + s] * scale;
    }
    __syncthreads();
    for (int d = t; d < D2_; d += 256) {
        float acc = 0.f;
        for (int i = 0; i < n; i++) {
            int s = sL[i];
            float ev = (d < 1024) ? encoded[((size_t)(b * S_ + s)) * 1024 + d] : bin[b * S_ + s];
            acc += aL[i] * ev;
        }
        out2[b * D2_ + d] = acc;
    }
}

extern "C" void kernel_launch(void* const* d_in, const int* in_sizes, int n_in,
                              void* d_out, int out_size, void* d_ws, size_t ws_size,
                              hipStream_t stream) {
    const int*   input_idx = (const int*)d_in[0];
    const float* encoded   = (const float*)d_in[1];
    const int*   enc_idx   = (const int*)d_in[2];
    const float* prev      = (const float*)d_in[3];
    const float* weighted  = (const float*)d_in[4];
    const float* bin       = (const float*)d_in[5];
    const int*   order     = (const int*)d_in[6];
    const float* embed     = (const float*)d_in[7];
    const float* W_ih      = (const float*)d_in[8];
    const float* b_ih      = (const float*)d_in[9];
    const float* W_hh      = (const float*)d_in[10];
    const float* b_hh      = (const float*)d_in[11];
    const float* Wo_w      = (const float*)d_in[12];
    const float* Wo_b      = (const float*)d_in[13];
    const float* Wc_w      = (const float*)d_in[14];
    const float* Wc_b      = (const float*)d_in[15];
    const float* Ws_w      = (const float*)d_in[16];
    const float* Ws_b      = (const float*)d_in[17];

    float* out  = (float*)d_out;
    float* out1 = out + B_ * VO_;             // state
    float* out2 = out1 + B_ * H_;             // weighted_out

    float* ws_f     = (float*)d_ws;
    float* w_state  = ws_f;                   // 16384
    float* w_prev   = ws_f + 16384;           // 16384
    float* w_weff   = ws_f + 32768;           // 35968
    float* w_x      = ws_f + 68736;           // 45056
    float* w_gi     = ws_f + 113792;          // 49152
    float* w_gh     = ws_f + 162944;          // 49152
    float* w_scores = ws_f + 212096;          // 1056768
    float* w_probc  = ws_f + 1268864;         // 32768
    float* w_partA  = ws_f + 1301632;         // 512
    float* w_partC  = ws_f + 1302144;         // 512
    float* w_rowinv = ws_f + 1302656;         // 32
    float* w_invgc  = ws_f + 1302688;         // 1
    int*   w_cnt    = (int*)(ws_f + 1302720); // 32
    int*   w_list   = w_cnt + 32;             // 32768
    unsigned short* w_bpack = (unsigned short*)((char*)d_ws + 5342080); // 589824 ushort

    k_prep0<<<32, 256, 0, stream>>>(order, prev, weighted, encoded, bin, Ws_w, Ws_b, w_prev, w_weff);
    k_build_x<<<176, 256, 0, stream>>>(input_idx, embed, w_weff, w_x);
    k_pack_wc<<<2304, 256, 0, stream>>>(Wc_w, w_bpack);
    k_gi<<<768, 256, 16 * INP_ * sizeof(float), stream>>>(w_x, W_ih, b_ih, w_gi);
    k_gh<<<384, 256, B_ * H_ * sizeof(float), stream>>>(w_prev, W_hh, b_hh, w_gh);
    k_gate<<<64, 256, 0, stream>>>(w_gi, w_gh, w_prev, w_state, out1);
    k_scoreg<<<512, 256, B_ * H_ * sizeof(float), stream>>>(w_state, Wo_w, Wo_b, w_scores);
    k_sc<<<512, 512, 0, stream>>>(encoded, bin, w_bpack, Wc_b, w_state, enc_idx, w_scores);
    k_exp<<<512, 256, 0, stream>>>(w_scores, w_partA, w_partC);
    k_combine<<<1, 512, 0, stream>>>(w_partA, w_partC, w_rowinv, w_invgc, w_cnt, w_list, enc_idx, input_idx);
    k_write<<<4128, 256, 0, stream>>>(w_scores, w_rowinv, out, w_probc);
    k_oov<<<2, 256, 0, stream>>>(out);
    k_scatter<<<128, 256, 0, stream>>>(w_probc, enc_idx, out);
    k_wo<<<32, 256, 0, stream>>>(w_probc, w_list, w_cnt, w_invgc, encoded, bin, out2);
}

// Round 2
// 440.193 us; speedup vs baseline: 1.2766x; 1.2766x over previous
//
#include <hip/hip_runtime.h>

#define B_   32
#define S_   1024
#define V_   32000
#define E_   256
#define H_   512
#define D2_  1124
#define IN_  1380
#define INP_ 1408
#define G3_  1536
#define NV_  33024   // V + S
#define VO_  32012   // V + MAX_OOVS
#define NKT_ 36      // K tiles of 32 covering 1152 (1124 padded)

typedef __bf16 bf16x8 __attribute__((ext_vector_type(8)));
typedef float  f32x4  __attribute__((ext_vector_type(4)));

static __device__ __forceinline__ unsigned short f2bf(float f) {
    union { float f; unsigned int u; } v; v.f = f;
    unsigned int u = v.u;
    unsigned int r = (u + 0x7FFFu + ((u >> 16) & 1u)) >> 16;  // RNE
    return (unsigned short)r;
}

// pack two f32 (as u32 bits) into two bf16 (round half up)
static __device__ __forceinline__ unsigned int pkbf(unsigned int a, unsigned int b) {
    return ((a + 0x8000u) >> 16) | ((b + 0x8000u) & 0xffff0000u);
}

// ---------------- order handling: effective prev_state / weighted ----------------
__global__ void k_prep0(const int* order, const float* prev, const float* weighted,
                        const float* encoded, const float* bin,
                        const float* Ws_w, const float* Ws_b,
                        float* prev_eff, float* weff) {
    int b = blockIdx.x, t = threadIdx.x;
    if (order[0] != 0) {
        for (int i = t; i < H_;  i += 256) prev_eff[b * H_ + i] = prev[b * H_ + i];
        for (int i = t; i < D2_; i += 256) weff[b * D2_ + i] = weighted[b * D2_ + i];
    } else {
        for (int i = t; i < D2_; i += 256) weff[b * D2_ + i] = 0.0f;
        const float* encrow = encoded + ((size_t)(b * S_ + (S_ - 1))) * 1024;
        float bv = bin[b * S_ + (S_ - 1)];
        for (int h = t; h < H_; h += 256) {
            float acc = Ws_b[h];
            const float* wr = Ws_w + (size_t)h * D2_;
            for (int d = 0; d < 1024; d++) acc += encrow[d] * wr[d];
            for (int d = 1024; d < D2_; d++) acc += bv * wr[d];
            prev_eff[b * H_ + h] = acc;
        }
    }
}

// ---------------- build x = [emb, weighted], padded to 1408 with zeros ----------------
__global__ void k_build_x(const int* input_idx, const float* embed, const float* weff, float* x) {
    int idx = blockIdx.x * 256 + threadIdx.x;   // 32*1408 exact
    int b = idx / INP_, d = idx % INP_;
    float v;
    if (d < E_)        v = embed[(size_t)input_idx[b] * E_ + d];
    else if (d < IN_)  v = weff[b * D2_ + (d - E_)];
    else               v = 0.0f;
    x[idx] = v;
}

// ---------------- pack Wc_w into MFMA B-fragment layout (bf16) ----------------
// bpack[((kt*32 + ht)*64 + lane)*8 + j] = Wc_w[ht*16 + (lane&15)][kt*32 + (lane>>4)*8 + j]
__global__ void k_pack_wc(const float* Wc_w, unsigned short* bpack) {
    int idx = blockIdx.x * 256 + threadIdx.x;   // 589824 exact
    int j = idx & 7, lane = (idx >> 3) & 63, ht = (idx >> 9) & 31, kt = idx >> 14;
    int h = ht * 16 + (lane & 15);
    int k = kt * 32 + (lane >> 4) * 8 + j;
    float v = (k < D2_) ? Wc_w[(size_t)h * D2_ + k] : 0.0f;
    bpack[idx] = f2bf(v);
}

// ---------------- gi = x @ W_ih.T + b_ih ----------------
__global__ void k_gi(const float* x, const float* W_ih, const float* b_ih, float* gi) {
    extern __shared__ float smemF[];            // 16 * 1408 floats
    int t = threadIdx.x;
    int bh = blockIdx.x & 1;
    int hq = blockIdx.x >> 1;
    const float4* xg = (const float4*)(x + (size_t)bh * 16 * INP_);
    float4* xl4 = (float4*)smemF;
    for (int j = t; j < 16 * INP_ / 4; j += 256) xl4[j] = xg[j];
    __syncthreads();
    int w = t >> 6, l = t & 63;
    int h3 = hq * 4 + w;
    const float* wr = W_ih + (size_t)h3 * IN_;
    float4 wv[6];
#pragma unroll
    for (int i = 0; i < 6; i++) {
        int k = 4 * l + 256 * i;
        if (k + 3 < IN_) wv[i] = *(const float4*)(wr + k);
        else {
            float a0 = (k     < IN_) ? wr[k]     : 0.f;
            float a1 = (k + 1 < IN_) ? wr[k + 1] : 0.f;
            float a2 = (k + 2 < IN_) ? wr[k + 2] : 0.f;
            float a3 = (k + 3 < IN_) ? wr[k + 3] : 0.f;
            wv[i] = make_float4(a0, a1, a2, a3);
        }
    }
    float bias = b_ih[h3];
    for (int bb = 0; bb < 16; bb++) {
        const float4* xr = xl4 + bb * (INP_ / 4);
        float p = 0.f;
#pragma unroll
        for (int i = 0; i < 6; i++) {
            int k = 4 * l + 256 * i;
            if (k < INP_) {
                float4 xv = xr[l + 64 * i];
                p += wv[i].x * xv.x + wv[i].y * xv.y + wv[i].z * xv.z + wv[i].w * xv.w;
            }
        }
#pragma unroll
        for (int off = 32; off >= 1; off >>= 1) p += __shfl_xor(p, off, 64);
        if (l == 0) gi[(bh * 16 + bb) * G3_ + h3] = p + bias;
    }
}

// ---------------- gh = prev_eff @ W_hh.T + b_hh ----------------
__global__ void k_gh(const float* prev_eff, const float* W_hh, const float* b_hh, float* gh) {
    extern __shared__ float smemF[];            // 32*512 floats
    int t = threadIdx.x;
    const float4* pg = (const float4*)prev_eff;
    float4* pl4 = (float4*)smemF;
    for (int j = t; j < B_ * H_ / 4; j += 256) pl4[j] = pg[j];
    __syncthreads();
    int w = t >> 6, l = t & 63;
    int h3 = blockIdx.x * 4 + w;
    const float* wr = W_hh + (size_t)h3 * H_;
    float4 w0 = *(const float4*)(wr + 4 * l);
    float4 w1 = *(const float4*)(wr + 256 + 4 * l);
    float bias = b_hh[h3];
    for (int bb = 0; bb < B_; bb++) {
        const float* pr = smemF + bb * H_;
        float4 s0 = *(const float4*)(pr + 4 * l);
        float4 s1 = *(const float4*)(pr + 256 + 4 * l);
        float p = w0.x * s0.x + w0.y * s0.y + w0.z * s0.z + w0.w * s0.w
                + w1.x * s1.x + w1.y * s1.y + w1.z * s1.z + w1.w * s1.w;
#pragma unroll
        for (int off = 32; off >= 1; off >>= 1) p += __shfl_xor(p, off, 64);
        if (l == 0) gh[bb * G3_ + h3] = p + bias;
    }
}

// ---------------- GRU gates -> state ----------------
__global__ void k_gate(const float* gi, const float* gh, const float* prev_eff,
                       float* state, float* out_state) {
    int idx = blockIdx.x * 256 + threadIdx.x;   // 16384 exact
    int b = idx >> 9, h = idx & 511;
    float ir = gi[b * G3_ + h],           hr = gh[b * G3_ + h];
    float iz = gi[b * G3_ + H_ + h],      hz = gh[b * G3_ + H_ + h];
    float in_ = gi[b * G3_ + 2 * H_ + h], hn = gh[b * G3_ + 2 * H_ + h];
    float r = 1.0f / (1.0f + expf(-(ir + hr)));
    float z = 1.0f / (1.0f + expf(-(iz + hz)));
    float n = tanhf(in_ + r * hn);
    float st = (1.0f - z) * n + z * prev_eff[idx];
    state[idx] = st;
    out_state[idx] = st;
}

// ---------------- score_g = state @ Wo_w.T + Wo_b via MFMA ----------------
// grid 500 blocks x 256 thr (4 waves). Wave w: N-tile of 16 rows of Wo_w, M=32 (all batches).
// A (state) staged once to LDS in bf16 A-frag-friendly layout, row stride 520 (bank-safe).
// B (Wo_w) read f32 from global, packed to bf16 in registers.
__global__ void __launch_bounds__(256) k_scoreg(const float* state, const float* Wo_w,
                                                const float* Wo_b, float* scores) {
    __shared__ unsigned short Abf[32 * 520];
    int t = threadIdx.x;
    {
        int m = t & 31, g = t >> 5;                 // 32 rows x 8 col-groups of 64
        const float4* src = (const float4*)(state + m * 512 + g * 64);
        unsigned short* dst = &Abf[m * 520 + g * 64];
#pragma unroll
        for (int i = 0; i < 16; i++) {
            float4 v = src[i];
            ushort4 p; p.x = f2bf(v.x); p.y = f2bf(v.y); p.z = f2bf(v.z); p.w = f2bf(v.w);
            *(ushort4*)(dst + i * 4) = p;
        }
    }
    __syncthreads();
    int w = t >> 6, l = t & 63;
    int q = l >> 4, m16 = l & 15;
    int n = blockIdx.x * 64 + w * 16 + m16;
    const uint4* wrow = (const uint4*)(Wo_w + (size_t)n * 512 + q * 8);
    f32x4 acc0 = {0.f, 0.f, 0.f, 0.f}, acc1 = {0.f, 0.f, 0.f, 0.f};
#pragma unroll
    for (int kt = 0; kt < 16; kt++) {
        uint4 w0 = wrow[kt * 8];
        uint4 w1 = wrow[kt * 8 + 1];
        int4 pb;
        pb.x = (int)pkbf(w0.x, w0.y); pb.y = (int)pkbf(w0.z, w0.w);
        pb.z = (int)pkbf(w1.x, w1.y); pb.w = (int)pkbf(w1.z, w1.w);
        bf16x8 bv = *(bf16x8*)&pb;
        bf16x8 a0 = *(const bf16x8*)&Abf[m16 * 520 + kt * 32 + q * 8];
        bf16x8 a1 = *(const bf16x8*)&Abf[(16 + m16) * 520 + kt * 32 + q * 8];
        acc0 = __builtin_amdgcn_mfma_f32_16x16x32_bf16(a0, bv, acc0, 0, 0, 0);
        acc1 = __builtin_amdgcn_mfma_f32_16x16x32_bf16(a1, bv, acc1, 0, 0, 0);
    }
    float wb = Wo_b[n];
#pragma unroll
    for (int r = 0; r < 4; r++) {
        scores[(q * 4 + r) * NV_ + n]        = acc0[r] + wb;
        scores[(16 + q * 4 + r) * NV_ + n]   = acc1[r] + wb;
    }
}

// ---------------- fused sc = tanh(enc@Wc_w.T + Wc_b); score_c = tanh(sc . state) + mask --------
// grid: 32 b * 16 s-tiles(64), block 512 threads (8 waves); wave w covers h in [w*64, w*64+64)
// Encoded tile for step kt+1 is prefetched into registers while step kt computes.
__global__ void __launch_bounds__(512) k_sc(
    const float* encoded, const float* bin, const unsigned short* bpack,
    const float* Wc_b, const float* state, const int* enc_idx, float* scores) {
    __shared__ unsigned short Albf[64 * 40];    // 64 s rows, 32 k + pad 8 (16B-aligned rows)
    __shared__ float partL[8][64];
    int t = threadIdx.x;
    int b = blockIdx.x >> 4;
    int s0 = (blockIdx.x & 15) * 64;
    int w = t >> 6, l = t & 63;
    int q = l >> 4, m = l & 15;

    f32x4 acc[4][4];
#pragma unroll
    for (int i = 0; i < 4; i++)
#pragma unroll
        for (int j2 = 0; j2 < 4; j2++) { acc[i][j2][0]=0.f; acc[i][j2][1]=0.f; acc[i][j2][2]=0.f; acc[i][j2][3]=0.f; }

    int s_l = t >> 3, k4 = (t & 7) * 4;
    const float* encbase = encoded + ((size_t)(b * S_ + s0 + s_l)) * 1024;
    float binv = bin[b * S_ + s0 + s_l];

    float4 nxt = *(const float4*)(encbase + k4);    // kt = 0 tile
    for (int kt = 0; kt < NKT_; kt++) {
        ushort4 pk;
        if (kt < 32) {
            pk.x = f2bf(nxt.x); pk.y = f2bf(nxt.y); pk.z = f2bf(nxt.z); pk.w = f2bf(nxt.w);
        } else {
            int k = kt * 32 + k4;
            pk.x = f2bf((k     < D2_) ? binv : 0.f);
            pk.y = f2bf((k + 1 < D2_) ? binv : 0.f);
            pk.z = f2bf((k + 2 < D2_) ? binv : 0.f);
            pk.w = f2bf((k + 3 < D2_) ? binv : 0.f);
        }
        *(ushort4*)&Albf[s_l * 40 + k4] = pk;
        __syncthreads();
        if (kt + 1 < 32)
            nxt = *(const float4*)(encbase + (kt + 1) * 32 + k4);   // prefetch next tile

        bf16x8 av[4], bv[4];
#pragma unroll
        for (int st = 0; st < 4; st++)
            av[st] = *(const bf16x8*)&Albf[(st * 16 + m) * 40 + q * 8];
#pragma unroll
        for (int jj = 0; jj < 4; jj++)
            bv[jj] = *(const bf16x8*)&bpack[(((size_t)kt * 32 + (w * 4 + jj)) * 64 + l) * 8];
#pragma unroll
        for (int st = 0; st < 4; st++)
#pragma unroll
            for (int jj = 0; jj < 4; jj++)
                acc[st][jj] = __builtin_amdgcn_mfma_f32_16x16x32_bf16(av[st], bv[jj], acc[st][jj], 0, 0, 0);
        __syncthreads();
    }

    // epilogue: val(s) = sum_h tanh(sc + bias_h) * state_h, reduce 16 lanes + 8 waves
    float hbias[4], hstate[4];
#pragma unroll
    for (int jj = 0; jj < 4; jj++) {
        int h = w * 64 + jj * 16 + m;
        hbias[jj]  = Wc_b[h];
        hstate[jj] = state[b * H_ + h];
    }
#pragma unroll
    for (int st = 0; st < 4; st++) {
#pragma unroll
        for (int r = 0; r < 4; r++) {
            float val = 0.f;
#pragma unroll
            for (int jj = 0; jj < 4; jj++)
                val += tanhf(acc[st][jj][r] + hbias[jj]) * hstate[jj];
            val += __shfl_xor(val, 1, 64);
            val += __shfl_xor(val, 2, 64);
            val += __shfl_xor(val, 4, 64);
            val += __shfl_xor(val, 8, 64);
            if (m == 0) partL[w][st * 16 + q * 4 + r] = val;
        }
    }
    __syncthreads();
    if (t < 64) {
        float tot = 0.f;
#pragma unroll
        for (int ww = 0; ww < 8; ww++) tot += partL[ww][t];
        int s = s0 + t;
        int ei = enc_idx[b * S_ + s];
        scores[b * NV_ + V_ + s] = tanhf(tot) + (ei == 0 ? -1000.0f : 0.0f);
    }
}

// ---------------- exp pass (in place) + partial sums ----------------
__global__ void k_exp(float* scores, float* partA, float* partC) {
    int blk = blockIdx.x;                       // 512 = 32 b * 16 chunks
    int b = blk >> 4, c = blk & 15;
    int t = threadIdx.x;
    float sa = 0.f, sc2 = 0.f;
    int base = b * NV_ + c * 2064;
    for (int i = t; i < 2064; i += 256) {
        float e = expf(scores[base + i]);
        scores[base + i] = e;
        sa += e;
        if (c * 2064 + i >= V_) sc2 += e;
    }
#pragma unroll
    for (int off = 32; off >= 1; off >>= 1) {
        sa  += __shfl_xor(sa, off, 64);
        sc2 += __shfl_xor(sc2, off, 64);
    }
    __shared__ float rA[4], rC[4];
    int w = t >> 6, l = t & 63;
    if (l == 0) { rA[w] = sa; rC[w] = sc2; }
    __syncthreads();
    if (t == 0) {
        partA[blk] = rA[0] + rA[1] + rA[2] + rA[3];
        partC[blk] = rC[0] + rC[1] + rC[2] + rC[3];
    }
}

// ---------------- combine: row sums, global c-sum, match count/list ----------------
__global__ void k_combine(const float* partA, const float* partC, float* rowinv, float* invgc,
                          int* cnt, int* list, const int* enc_idx, const int* input_idx) {
    __shared__ float rs[32], rc[32];
    int t = threadIdx.x;
    if (t < 32) {
        float a = 0.f, c = 0.f;
        for (int j = 0; j < 16; j++) { a += partA[t * 16 + j]; c += partC[t * 16 + j]; }
        rs[t] = a; rc[t] = c;
        rowinv[t] = 1.0f / a;
        cnt[t] = 0;
    }
    __syncthreads();
    if (t == 0) {
        float g = 0.f;
        for (int b = 0; b < 32; b++) g += rc[b] / rs[b];
        invgc[0] = 1.0f / g;
    }
    for (int i = t; i < B_ * S_; i += 512) {
        int b = i >> 10;
        if (enc_idx[i] == input_idx[b]) {
            int p = atomicAdd(&cnt[b], 1);
            list[b * S_ + p] = i & 1023;
        }
    }
}

// ---------------- normalize: prob_g -> out, prob_c -> ws ----------------
__global__ void k_write(const float* scores, const float* rowinv, float* out, float* probc) {
    int idx = blockIdx.x * 256 + threadIdx.x;   // 32*33024 exact
    int b = idx / NV_, v = idx - b * NV_;
    float p = scores[idx] * rowinv[b];
    if (v < V_) out[b * VO_ + v] = p;
    else        probc[b * S_ + (v - V_)] = p;
}

__global__ void k_oov(float* out) {
    int idx = blockIdx.x * 256 + threadIdx.x;
    if (idx < B_ * 12) {
        int b = idx / 12, j = idx - b * 12;
        out[b * VO_ + V_ + j] = 0.0001f;
    }
}

// ---------------- scatter prob_c into out ----------------
__global__ void k_scatter(const float* probc, const int* enc_idx, float* out) {
    int idx = blockIdx.x * 256 + threadIdx.x;   // 32768 exact
    int b = idx >> 10;
    atomicAdd(&out[b * VO_ + enc_idx[idx]], probc[idx]);
}

// ---------------- weighted_out via sparse match list ----------------
__global__ void k_wo(const float* probc, const int* list, const int* cnt, const float* invgc,
                     const float* encoded, const float* bin, float* out2) {
    int b = blockIdx.x, t = threadIdx.x;
    __shared__ float aL[1024];
    __shared__ int   sL[1024];
    int n = cnt[b];
    float scale = invgc[0] * (n > 1 ? 1.0f / (float)n : 1.0f);
    for (int i = t; i < n; i += 256) {
        int s = list[b * S_ + i];
        sL[i] = s;
        aL[i] = probc[b * S_ + s] * scale;
    }
    __syncthreads();
    for (int d = t; d < D2_; d += 256) {
        float acc = 0.f;
        for (int i = 0; i < n; i++) {
            int s = sL[i];
            float ev = (d < 1024) ? encoded[((size_t)(b * S_ + s)) * 1024 + d] : bin[b * S_ + s];
            acc += aL[i] * ev;
        }
        out2[b * D2_ + d] = acc;
    }
}

extern "C" void kernel_launch(void* const* d_in, const int* in_sizes, int n_in,
                              void* d_out, int out_size, void* d_ws, size_t ws_size,
                              hipStream_t stream) {
    const int*   input_idx = (const int*)d_in[0];
    const float* encoded   = (const float*)d_in[1];
    const int*   enc_idx   = (const int*)d_in[2];
    const float* prev      = (const float*)d_in[3];
    const float* weighted  = (const float*)d_in[4];
    const float* bin       = (const float*)d_in[5];
    const int*   order     = (const int*)d_in[6];
    const float* embed     = (const float*)d_in[7];
    const float* W_ih      = (const float*)d_in[8];
    const float* b_ih      = (const float*)d_in[9];
    const float* W_hh      = (const float*)d_in[10];
    const float* b_hh      = (const float*)d_in[11];
    const float* Wo_w      = (const float*)d_in[12];
    const float* Wo_b      = (const float*)d_in[13];
    const float* Wc_w      = (const float*)d_in[14];
    const float* Wc_b      = (const float*)d_in[15];
    const float* Ws_w      = (const float*)d_in[16];
    const float* Ws_b      = (const float*)d_in[17];

    float* out  = (float*)d_out;
    float* out1 = out + B_ * VO_;             // state
    float* out2 = out1 + B_ * H_;             // weighted_out

    float* ws_f     = (float*)d_ws;
    float* w_state  = ws_f;                   // 16384
    float* w_prev   = ws_f + 16384;           // 16384
    float* w_weff   = ws_f + 32768;           // 35968
    float* w_x      = ws_f + 68736;           // 45056
    float* w_gi     = ws_f + 113792;          // 49152
    float* w_gh     = ws_f + 162944;          // 49152
    float* w_scores = ws_f + 212096;          // 1056768
    float* w_probc  = ws_f + 1268864;         // 32768
    float* w_partA  = ws_f + 1301632;         // 512
    float* w_partC  = ws_f + 1302144;         // 512
    float* w_rowinv = ws_f + 1302656;         // 32
    float* w_invgc  = ws_f + 1302688;         // 1
    int*   w_cnt    = (int*)(ws_f + 1302720); // 32
    int*   w_list   = w_cnt + 32;             // 32768
    unsigned short* w_bpack = (unsigned short*)((char*)d_ws + 5342080); // 589824 ushort

    k_prep0<<<32, 256, 0, stream>>>(order, prev, weighted, encoded, bin, Ws_w, Ws_b, w_prev, w_weff);
    k_build_x<<<176, 256, 0, stream>>>(input_idx, embed, w_weff, w_x);
    k_pack_wc<<<2304, 256, 0, stream>>>(Wc_w, w_bpack);
    k_gi<<<768, 256, 16 * INP_ * sizeof(float), stream>>>(w_x, W_ih, b_ih, w_gi);
    k_gh<<<384, 256, B_ * H_ * sizeof(float), stream>>>(w_prev, W_hh, b_hh, w_gh);
    k_gate<<<64, 256, 0, stream>>>(w_gi, w_gh, w_prev, w_state, out1);
    k_scoreg<<<500, 256, 0, stream>>>(w_state, Wo_w, Wo_b, w_scores);
    k_sc<<<512, 512, 0, stream>>>(encoded, bin, w_bpack, Wc_b, w_state, enc_idx, w_scores);
    k_exp<<<512, 256, 0, stream>>>(w_scores, w_partA, w_partC);
    k_combine<<<1, 512, 0, stream>>>(w_partA, w_partC, w_rowinv, w_invgc, w_cnt, w_list, enc_idx, input_idx);
    k_write<<<4128, 256, 0, stream>>>(w_scores, w_rowinv, out, w_probc);
    k_oov<<<2, 256, 0, stream>>>(out);
    k_scatter<<<128, 256, 0, stream>>>(w_probc, enc_idx, out);
    k_wo<<<32, 256, 0, stream>>>(w_probc, w_list, w_cnt, w_invgc, encoded, bin, out2);
}